// Round 1
// baseline (82.049 us; speedup 1.0000x reference)
//
#include <hip/hip_runtime.h>
#include <stdint.h>

#define NB 4096     // B
#define ND 256      // D

typedef __attribute__((ext_vector_type(8))) short short8;   // 8 bf16 = 4 VGPR
typedef __attribute__((ext_vector_type(4))) float f32x4;

// fp32 -> bf16 RNE (inputs are finite Gaussians; no NaN handling needed)
__device__ __forceinline__ unsigned short f2bf(float f) {
    unsigned int u = __float_as_uint(f);
    u += 0x7FFFu + ((u >> 16) & 1u);
    return (unsigned short)(u >> 16);
}

// async global->LDS, 16B per lane. lds dest = wave-uniform base + lane*16.
__device__ __forceinline__ void gload16(const void* g, void* lds_uniform) {
    __builtin_amdgcn_global_load_lds(
        (const __attribute__((address_space(1))) void*)(uintptr_t)g,
        (__attribute__((address_space(3))) void*)(unsigned int)(uintptr_t)lds_uniform,
        16, 0, 0);
}

// ---------------- prep: 1/||row||, bf16 copies, zero loss accumulator ----------------
__global__ void __launch_bounds__(256) prep_kernel(
    const float* __restrict__ A, const float* __restrict__ Bf,
    unsigned short* __restrict__ Abf, unsigned short* __restrict__ Bbf,
    float* __restrict__ rna, float* __restrict__ rnb, float* __restrict__ lossws)
{
    if (blockIdx.x == 0 && threadIdx.x == 0) lossws[0] = 0.0f;
    int gw   = (blockIdx.x * 256 + threadIdx.x) >> 6;   // global wave id 0..8191
    int lane = threadIdx.x & 63;
    const float* src; unsigned short* dst; float* rn; int row;
    if (gw < NB) { src = A;  dst = Abf; rn = rna; row = gw; }
    else         { src = Bf; dst = Bbf; rn = rnb; row = gw - NB; }

    float4 v = reinterpret_cast<const float4*>(src + (size_t)row * ND)[lane];
    float ss = v.x * v.x + v.y * v.y + v.z * v.z + v.w * v.w;
    #pragma unroll
    for (int off = 32; off > 0; off >>= 1) ss += __shfl_down(ss, off);
    if (lane == 0) rn[row] = 1.0f / sqrtf(fmaxf(ss, 1e-30f));

    ushort4 u;
    u.x = f2bf(v.x); u.y = f2bf(v.y); u.z = f2bf(v.z); u.w = f2bf(v.w);
    reinterpret_cast<ushort4*>(dst + (size_t)row * ND)[lane] = u;
}

// ---------------- fused GEMM + diagonal-permuted epilogue + BCE loss ----------------
// Block: 128x128 (k,j) tile, 4 waves (2x2), each wave a 64x64 subtile.
// acc is rerouted through a diagonal-bijective LDS layout so global stores are
// contiguous runs of out[s*NB + k] (k consecutive).
__global__ void __launch_bounds__(256) gemm_kernel(
    const unsigned short* __restrict__ Abf, const unsigned short* __restrict__ Bbf,
    const float* __restrict__ rna, const float* __restrict__ rnb,
    const float* __restrict__ labels, float* __restrict__ out,
    float* __restrict__ lossws)
{
    __shared__ __align__(16) char smem[65536]; // staging A[0,16K)+B[16K,32K); epilogue 4x16K

    const int tid = threadIdx.x;
    const int w = tid >> 6, lane = tid & 63;
    const int lane15 = lane & 15, lhi = lane >> 4;
    const int bk = blockIdx.x >> 5, bj = blockIdx.x & 31;
    const int k0 = bk << 7, j0 = bj << 7;
    const int mw = w >> 1, nw = w & 1;

    char* ldsA = smem;
    char* ldsB = smem + 16384;

    f32x4 acc[4][4];
    #pragma unroll
    for (int i = 0; i < 4; ++i)
        #pragma unroll
        for (int j = 0; j < 4; ++j) acc[i][j] = (f32x4)0.0f;

    const int slotbase = w * 256; // 256 16B-slots per wave per tile (1024 total = 16KB)

    for (int kt = 0; kt < 4; ++kt) {          // K = 256 in 4 chunks of BK=64
        #pragma unroll
        for (int i = 0; i < 4; ++i) {
            int slot0 = slotbase + i * 64;    // wave-uniform
            int slot  = slot0 + lane;         // this lane's 16B slot
            int row = slot >> 3;              // 8 chunks of 16B per 128B row
            int sch = (slot & 7) ^ (row & 7); // pre-swizzled source chunk
            gload16(Abf + (size_t)(k0 + row) * ND + kt * 64 + sch * 8, ldsA + slot0 * 16);
            gload16(Bbf + (size_t)(j0 + row) * ND + kt * 64 + sch * 8, ldsB + slot0 * 16);
        }
        __syncthreads();   // drains vmcnt for global_load_lds

        #pragma unroll
        for (int ks = 0; ks < 2; ++ks) {      // two K=32 MFMA steps per BK=64
            short8 af[4], bfr[4];
            #pragma unroll
            for (int mi = 0; mi < 4; ++mi) {
                int row = (mw << 6) + (mi << 4) + lane15;
                int ch  = (ks * 4 + lhi) ^ (row & 7);
                af[mi] = *reinterpret_cast<const short8*>(ldsA + row * 128 + ch * 16);
            }
            #pragma unroll
            for (int ni = 0; ni < 4; ++ni) {
                int row = (nw << 6) + (ni << 4) + lane15;
                int ch  = (ks * 4 + lhi) ^ (row & 7);
                bfr[ni] = *reinterpret_cast<const short8*>(ldsB + row * 128 + ch * 16);
            }
            #pragma unroll
            for (int mi = 0; mi < 4; ++mi)
                #pragma unroll
                for (int ni = 0; ni < 4; ++ni)
                    acc[mi][ni] = __builtin_amdgcn_mfma_f32_16x16x32_bf16(
                        af[mi], bfr[ni], acc[mi][ni], 0, 0, 0);
        }
        __syncthreads();   // staging buffers reusable
    }

    // ---- epilogue: acc -> diagonal LDS (per-wave 64x64, bijective) ----
    // element (kappa, iota) stored at LDS[(iota-kappa)&63][kappa ^ (dr&31)]
    float* dwave = reinterpret_cast<float*>(smem) + (w << 12); // 16KB per wave
    #pragma unroll
    for (int mi = 0; mi < 4; ++mi) {
        #pragma unroll
        for (int ni = 0; ni < 4; ++ni) {
            #pragma unroll
            for (int e = 0; e < 4; ++e) {
                int kap = (mi << 4) + (lhi << 2) + e;   // local k (C/D row)
                int io  = (ni << 4) + lane15;           // local j (C/D col)
                int dr  = (io - kap) & 63;
                dwave[(dr << 6) + (kap ^ (dr & 31))] = acc[mi][ni][e];
            }
        }
    }
    __syncthreads();

    const int kw0 = k0 + (mw << 6);
    const int jw0 = j0 + (nw << 6);
    const float rna_l = rna[kw0 + lane];
    const float rnb_l = rnb[jw0 + lane];
    const float lab_l = labels[kw0 + lane];
    const int sbase = (jw0 - kw0 + NB) & (NB - 1);

    float lacc = 0.0f;
    #pragma unroll 4
    for (int r = 0; r < 64; ++r) {
        // LDS row r, logical column kappa = lane  (iota = (lane+r)&63)
        float d = dwave[(r << 6) + (lane ^ (r & 31))];
        int wrap = ((lane + r) >> 6) & 1;                       // iota wrapped past 64
        int s = (sbase + r - (wrap << 6) + NB) & (NB - 1);      // global shift index
        float rnbv = __shfl(rnb_l, (lane + r) & 63);
        float cosv = d * rna_l * rnbv;
        float x = fmaf(cosv, 0.5f, 0.5f);                       // logit in (0,1)
        out[(size_t)s * NB + (kw0 + lane)] = x;                 // 2 contiguous segments/row
        float l1p = fmaxf(__logf(1.0f - x), -100.0f);
        if (s == 0) {
            float lp = fmaxf(__logf(x), -100.0f);
            lacc += lab_l * lp + (1.0f - lab_l) * l1p;          // weight 1
        } else {
            lacc += 0.5f * l1p;                                 // weight NEG_WEIGHT
        }
    }
    #pragma unroll
    for (int off = 32; off > 0; off >>= 1) lacc += __shfl_down(lacc, off);
    if (lane == 0) atomicAdd(lossws, -lacc);
}

__global__ void finalize_kernel(const float* __restrict__ lossws, float* __restrict__ out) {
    out[(size_t)NB * NB] = lossws[0];
}

extern "C" void kernel_launch(void* const* d_in, const int* in_sizes, int n_in,
                              void* d_out, int out_size, void* d_ws, size_t ws_size,
                              hipStream_t stream) {
    (void)in_sizes; (void)n_in; (void)out_size; (void)ws_size;
    const float* A      = (const float*)d_in[0];
    const float* Bf     = (const float*)d_in[1];
    const float* labels = (const float*)d_in[2];
    float* out = (float*)d_out;

    char* ws = (char*)d_ws;
    unsigned short* Abf = (unsigned short*)ws;                                  // 2 MB
    unsigned short* Bbf = (unsigned short*)(ws + (size_t)2 * 1024 * 1024);      // 2 MB
    float* rna    = (float*)(ws + (size_t)4 * 1024 * 1024);                     // 16 KB
    float* rnb    = (float*)(ws + (size_t)4 * 1024 * 1024 + 16384);             // 16 KB
    float* lossws = (float*)(ws + (size_t)4 * 1024 * 1024 + 32768);             // 4 B

    hipLaunchKernelGGL(prep_kernel, dim3(2048), dim3(256), 0, stream,
                       A, Bf, Abf, Bbf, rna, rnb, lossws);
    hipLaunchKernelGGL(gemm_kernel, dim3(1024), dim3(256), 0, stream,
                       Abf, Bbf, rna, rnb, labels, out, lossws);
    hipLaunchKernelGGL(finalize_kernel, dim3(1), dim3(1), 0, stream, lossws, out);
}